// Round 7
// baseline (385.096 us; speedup 1.0000x reference)
//
#include <hip/hip_runtime.h>

// CAM_43344809951340: per-sample symmetric outer-product tanh attention.
// tanh(u) = 1 - 2/(1+e^{2u}); fold 2*SCALE*log2(e) into scaled av (xc),
// fold -2W into weights, hoist sum(W).
//
// Symmetric diagonal walk (validated R5/R6, absmax 9.8e-4): step k=31..1,
// lane r computes p = 1/(1+exp2(x_r * xc_{r+k})) once per unordered pair:
//   own-row:  p * wo_k,  wo_k = -2 W_{row_r}[(r+k)&63]   (LDS float2 .x)
//   mirror:   t = ror1(fma(p, wd_k, t)), wd_k = -2 W_{row_{r+k}}[r] (.y);
//             WAVE_ROR1 (0x13C) moves values toward higher lanes, so a
//             deposit at step k lands at lane r+k after its k rotations.
//   av operand a travels by ror1 from xc_{r+31} down to xc_{r+1}.
// Two samples (A,B) per wave iteration: independent chains fill the
// exp/rcp latency bubbles; each float2 weight read serves both.
//
// NEW vs R6: the [2][32][64] table was half-dead -- a lane with sel=lane>>5
// only ever touches s_P[sel][k][lane]. Merged to ONE [32][64] table with
// sel baked in per-lane: LDS 33 KB -> 16.5 KB, so blocks/CU 4 -> 8 and
// occupancy 4 -> 8 waves/SIMD (VGPR 60 <= 64). Math unchanged.

__device__ __forceinline__ float wave_ror1_f32(float v) {
    // D[i] = S[(i-1) & 63] — values move toward higher lanes
    return __int_as_float(__builtin_amdgcn_update_dpp(
        __float_as_int(v), __float_as_int(v), 0x13C, 0xF, 0xF, false));
}

__device__ __forceinline__ float sig2(float x, float a) {
    // 1/(1 + exp2(x*a))
    return __builtin_amdgcn_rcpf(1.0f + __builtin_amdgcn_exp2f(x * a));
}

__global__ __launch_bounds__(256, 8) void cam_kernel(
    const float* __restrict__ f1,
    const float* __restrict__ f2,
    const float* __restrict__ Wca,
    const float* __restrict__ Wcv,
    float* __restrict__ out,
    int B)
{
    // 2 * SCALE * log2(e) = 0.25 * 1.4426950408889634
    constexpr float C = 0.3606737602222409f;

    // s_Q[k][ln] = { -2*W_{sel(ln)}[(ln+k)&63], -2*W_{half((ln+k)&63)}[ln] }
    // with sel(ln)=ln>>5 baked in: each lane reads only its own column.
    __shared__ __align__(16) float2 s_Q[32][64];       // 16 KB
    __shared__ float s_wsum[2];

    const int tid  = threadIdx.x;
    const int lane = tid & 63;

    for (int idx = tid; idx < 32 * 64; idx += 256) {
        const int k   = idx >> 6;
        const int ln  = idx & 63;
        const int sel = ln >> 5;
        const int j   = (ln + k) & 63;
        s_Q[k][ln] = make_float2(
            -2.0f * (sel ? Wcv : Wca)[j],
            -2.0f * ((j < 32) ? Wca : Wcv)[ln]);
    }
    if (tid < 128) {                                   // row sums (waves 0,1)
        const int sel = tid >> 6;
        float s = (sel ? Wcv : Wca)[lane];
        #pragma unroll
        for (int off = 32; off > 0; off >>= 1) s += __shfl_xor(s, off, 64);
        if (lane == 0) s_wsum[sel] = s;
    }
    __syncthreads();

    const int sel = lane >> 5;                         // 0: audio, 1: visual half
    const float wsum = s_wsum[sel];
    const float2* __restrict__ Qp = &s_Q[0][lane];     // step k at Qp[k*64]
    const float* __restrict__ fbase = sel ? f2 : f1;
    const int col = lane & 31;

    const float w0  = Qp[0].x;                                // k=0 (diagonal)
    const float w32 = -2.0f * (sel ? Wcv : Wca)[lane ^ 32];   // k=32
    const int idx31 = ((lane + 31) & 63) << 2;         // bpermute byte indices
    const int idx32 = (lane ^ 32) << 2;

    const int gw     = (blockIdx.x * 256 + tid) >> 6;
    const int stride = (gridDim.x << 2) * 2;           // 2 samples per wave/iter

    int b = gw * 2;
    if (b >= B) return;                                // wave-uniform
    float xA = fbase[b * 32 + col];
    float xB = (b + 1 < B) ? fbase[(b + 1) * 32 + col] : 0.0f;

    while (b < B) {
        const int bn = b + stride;
        float xnA = 0.0f, xnB = 0.0f;
        if (bn < B) {                                  // prefetch next pair
            xnA = fbase[bn * 32 + col];
            if (bn + 1 < B) xnB = fbase[(bn + 1) * 32 + col];
        }

        const float xcA = xA * C;
        const float xcB = xB * C;
        float aA = __int_as_float(
            __builtin_amdgcn_ds_bpermute(idx31, __float_as_int(xcA)));
        float aB = __int_as_float(
            __builtin_amdgcn_ds_bpermute(idx31, __float_as_int(xcB)));
        const float a32A = __int_as_float(
            __builtin_amdgcn_ds_bpermute(idx32, __float_as_int(xcA)));
        const float a32B = __int_as_float(
            __builtin_amdgcn_ds_bpermute(idx32, __float_as_int(xcB)));

        // k=0 diagonal + k=32 (both lanes own-row), per sample
        float own0A = sig2(xA, xcA)  * w0;
        float own0B = sig2(xB, xcB)  * w0;
        float own1A = sig2(xA, a32A) * w32;
        float own1B = sig2(xB, a32B) * w32;

        float tA = 0.0f, tB = 0.0f;                    // traveling mirror accs
        #pragma unroll
        for (int k = 31; k >= 1; --k) {
            const float2 w2 = Qp[k * 64];              // ds_read_b64, imm offset
            const float pA = sig2(xA, aA);
            const float pB = sig2(xB, aB);
            if (k & 1) { own0A = fmaf(pA, w2.x, own0A); own0B = fmaf(pB, w2.x, own0B); }
            else       { own1A = fmaf(pA, w2.x, own1A); own1B = fmaf(pB, w2.x, own1B); }
            tA = wave_ror1_f32(fmaf(pA, w2.y, tA));
            aA = wave_ror1_f32(aA);
            tB = wave_ror1_f32(fmaf(pB, w2.y, tB));
            aB = wave_ror1_f32(aB);
        }
        // after the k=1 iteration each deposit has had exactly k rotations

        const float hA = fmaxf(wsum + xA + own0A + own1A + tA, 0.0f) * 0.1f;
        const float hB = fmaxf(wsum + xB + own0B + own1B + tB, 0.0f) * 0.1f;
        out[b * 64 + lane] = hA;
        if (b + 1 < B) out[(b + 1) * 64 + lane] = hB;

        b = bn;
        xA = xnA;
        xB = xnB;
    }
}

extern "C" void kernel_launch(void* const* d_in, const int* in_sizes, int n_in,
                              void* d_out, int out_size, void* d_ws, size_t ws_size,
                              hipStream_t stream) {
    const float* f1  = (const float*)d_in[0];
    const float* f2  = (const float*)d_in[1];
    const float* Wca = (const float*)d_in[2];
    const float* Wcv = (const float*)d_in[3];
    float* out = (float*)d_out;

    const int B = in_sizes[0] / 32;
    const int pairs = (B + 1) / 2;
    int blocks = (pairs + 3) / 4;       // 4 waves/block, 1 pair/wave minimum
    if (blocks > 2048) blocks = 2048;   // 8 blocks/CU (16.5 KB LDS) = 8 waves/SIMD
    if (blocks < 1) blocks = 1;

    cam_kernel<<<blocks, 256, 0, stream>>>(f1, f2, Wca, Wcv, out, B);
}

// Round 9
// 344.550 us; speedup vs baseline: 1.1177x; 1.1177x over previous
//
#include <hip/hip_runtime.h>
#include <math.h>

// CAM_43344809951340: per-sample symmetric outer-product tanh attention.
// H_row[r] = 0.1*relu( sum_j tanh(x_r * av_j / 8) * W_{row_r}[j] + x_r )
//
// Validated diagonal walk (R5-R7, absmax 9.8e-4): step k, lane r computes
// the pair (r, j=(r+k)&63) once:
//   own-row:  tanh * wox[k]  (wox[k] = W_{sel(r)}[(r+k)&63])
//   mirror:   t = ror1(fma(tanh, wdy[k], t))  (wdy[k] = W_{sel(j)}[r]);
//             WAVE_ROR1 (0x13C) moves values toward higher lanes, so a
//             deposit at step k lands at lane r+k after its k rotations.
// k=0 (diagonal) and k=32 (both lanes own-row) handled separately.
//
// NEW vs R6/R7:
//  * tanh via LDS lookup (1025-pt, [-4,4], linear interp, err<=6e-6; table
//    built on-device with tanhf). Kills the 2 quarter-rate transcendentals
//    per element (32 cy) that R6's counters showed were the issue floor.
//    |u|=|x*av|/8 <= ~3.4 < 4 for N(0,1) data; clamped anyway.
//  * weights preloaded into REGISTERS (fully unrolled, static indices)
//    under __launch_bounds__(256,4) = 128-VGPR budget. R7's 4x regression
//    was the compiler hoisting these loop-invariant LDS loads and spilling
//    under the 64-VGPR cap (VGPR=32 + 885MB FETCH = scratch signature).
//    Now the hoist is explicit and has registers to land in.
//  * inner loop: zero structured LDS reads; DS pipe only does the 2
//    interp gathers per step (+4 bpermutes per iteration).

__device__ __forceinline__ float wave_ror1_f32(float v) {
    // D[i] = S[(i-1) & 63] — values move toward higher lanes
    return __int_as_float(__builtin_amdgcn_update_dpp(
        __float_as_int(v), __float_as_int(v), 0x13C, 0xF, 0xF, false));
}

// tanh(x * av / 8) via table: idx = x*as + 512, as = 16*av  (128*S = 16)
__device__ __forceinline__ float tanh_lut(const float* __restrict__ tb,
                                          float x, float as) {
    float idxf = fmaf(x, as, 512.0f);
    idxf = fminf(fmaxf(idxf, 0.0f), 1023.0f);     // v_med3
    const int i = (int)idxf;
    const float fr = idxf - (float)i;
    const float lo = tb[i];
    const float hi = tb[i + 1];
    return fmaf(fr, hi - lo, lo);
}

__global__ __launch_bounds__(256, 4) void cam_kernel(
    const float* __restrict__ f1,
    const float* __restrict__ f2,
    const float* __restrict__ Wca,
    const float* __restrict__ Wcv,
    float* __restrict__ out,
    int B)
{
    // s_Q[k][ln] = { W_{sel(ln)}[(ln+k)&63], W_{half((ln+k)&63)}[ln] }
    __shared__ __align__(16) float2 s_Q[32][64];      // 16 KB (preload only)
    __shared__ float s_tanh[1025];                    // 4.1 KB

    const int tid  = threadIdx.x;
    const int lane = tid & 63;

    for (int i = tid; i <= 1024; i += 256)            // tanh((i-512)/128)
        s_tanh[i] = tanhf((float)(i - 512) * 0.0078125f);

    for (int idx = tid; idx < 32 * 64; idx += 256) {
        const int k   = idx >> 6;
        const int ln  = idx & 63;
        const int sel = ln >> 5;
        const int j   = (ln + k) & 63;
        s_Q[k][ln] = make_float2((sel ? Wcv : Wca)[j],
                                 ((j < 32) ? Wca : Wcv)[ln]);
    }
    __syncthreads();

    const int sel = lane >> 5;                        // 0: audio, 1: visual
    const float* __restrict__ fbase = sel ? f2 : f1;
    const float* __restrict__ tb = s_tanh;
    const int col = lane & 31;

    // ---- loop-invariant weights -> registers (static indices only) ----
    float wox[32], wdy[32];
    #pragma unroll
    for (int k = 0; k < 32; ++k) {
        const float2 w2 = s_Q[k][lane];
        wox[k] = w2.x;
        wdy[k] = w2.y;
    }
    const float w32 = (sel ? Wcv : Wca)[lane ^ 32];   // k=32 own weight

    const int idx31 = ((lane + 31) & 63) << 2;        // bpermute byte indices
    const int idx32 = (lane ^ 32) << 2;

    const int gw     = (blockIdx.x * 256 + tid) >> 6;
    const int stride = (gridDim.x << 2) * 2;          // 2 samples per wave/iter

    int b = gw * 2;
    if (b >= B) return;                               // wave-uniform
    float xA = fbase[b * 32 + col];
    float xB = (b + 1 < B) ? fbase[(b + 1) * 32 + col] : 0.0f;

    while (b < B) {
        const int bn = b + stride;
        float xnA = 0.0f, xnB = 0.0f;
        if (bn < B) {                                 // prefetch next pair
            xnA = fbase[bn * 32 + col];
            if (bn + 1 < B) xnB = fbase[(bn + 1) * 32 + col];
        }

        const float xsA = xA * 16.0f;                 // 16*av contribution
        const float xsB = xB * 16.0f;
        float aA = __int_as_float(                    // xs_{(r+31)&63}
            __builtin_amdgcn_ds_bpermute(idx31, __float_as_int(xsA)));
        float aB = __int_as_float(
            __builtin_amdgcn_ds_bpermute(idx31, __float_as_int(xsB)));
        const float a32A = __int_as_float(            // xs_{r^32}
            __builtin_amdgcn_ds_bpermute(idx32, __float_as_int(xsA)));
        const float a32B = __int_as_float(
            __builtin_amdgcn_ds_bpermute(idx32, __float_as_int(xsB)));

        // k=0 diagonal + k=32 (both lanes own-row), per sample
        float own0A = tanh_lut(tb, xA, xsA)  * wox[0];
        float own0B = tanh_lut(tb, xB, xsB)  * wox[0];
        float own1A = tanh_lut(tb, xA, a32A) * w32;
        float own1B = tanh_lut(tb, xB, a32B) * w32;

        float tA = 0.0f, tB = 0.0f;                   // traveling mirror accs
        #pragma unroll
        for (int k = 31; k >= 1; --k) {
            const float pA = tanh_lut(tb, xA, aA);
            const float pB = tanh_lut(tb, xB, aB);
            if (k & 1) { own0A = fmaf(pA, wox[k], own0A); own0B = fmaf(pB, wox[k], own0B); }
            else       { own1A = fmaf(pA, wox[k], own1A); own1B = fmaf(pB, wox[k], own1B); }
            tA = wave_ror1_f32(fmaf(pA, wdy[k], tA));
            aA = wave_ror1_f32(aA);
            tB = wave_ror1_f32(fmaf(pB, wdy[k], tB));
            aB = wave_ror1_f32(aB);
        }
        // after the k=1 iteration each deposit has had exactly k rotations

        const float hA = fmaxf(xA + own0A + own1A + tA, 0.0f) * 0.1f;
        const float hB = fmaxf(xB + own0B + own1B + tB, 0.0f) * 0.1f;
        out[b * 64 + lane] = hA;
        if (b + 1 < B) out[(b + 1) * 64 + lane] = hB;

        b = bn;
        xA = xnA;
        xB = xnB;
    }
}

extern "C" void kernel_launch(void* const* d_in, const int* in_sizes, int n_in,
                              void* d_out, int out_size, void* d_ws, size_t ws_size,
                              hipStream_t stream) {
    const float* f1  = (const float*)d_in[0];
    const float* f2  = (const float*)d_in[1];
    const float* Wca = (const float*)d_in[2];
    const float* Wcv = (const float*)d_in[3];
    float* out = (float*)d_out;

    const int B = in_sizes[0] / 32;
    const int pairs = (B + 1) / 2;
    int blocks = (pairs + 3) / 4;       // 4 waves/block, 1 pair/wave minimum
    if (blocks > 1024) blocks = 1024;   // 4 blocks/CU resident (VGPR-capped)
    if (blocks < 1) blocks = 1;

    cam_kernel<<<blocks, 256, 0, stream>>>(f1, f2, Wca, Wcv, out, B);
}

// Round 10
// 122.160 us; speedup vs baseline: 3.1524x; 2.8205x over previous
//
#include <hip/hip_runtime.h>
#include <math.h>

// CAM_43344809951340: per-sample symmetric outer-product tanh attention.
// H_row[r] = 0.1*relu( sum_j tanh(x_r * av_j / 8) * W_{row_r}[j] + x_r )
//
// Validated diagonal walk (R5/R6, absmax ~1e-3): step k=31..1, lane r
// computes the pair (r, j=(r+k)&63) once:
//   own-row:  p * w2.x   (w2.x = W_{sel(r)}[(r+k)&63], LDS ds_read_b64)
//   mirror:   t = ror1(fma(p, w2.y, t))  (w2.y = W_{sel(j)}[r]);
//             WAVE_ROR1 (0x13C) moves values toward higher lanes, so a
//             deposit at step k lands at lane r+k after its k rotations.
//   av operand a travels by ror1 from 32*x_{r+31} down to 32*x_{r+1}.
// k=0 (diagonal) and k=32 (both lanes own-row) handled separately.
//
// R10 changes, from R7/R9 post-mortems:
//  * tanh via 2048-pt NEAREST-NEIGHBOR LDS table over u in [-4,4]
//    (idx = round(256u+1024) = trunc(fma(x, 32*av, 1024.5)), clamped).
//    Err <= 1.95e-3 per tanh -> ~1e-3 in H (threshold 1.09e-2). Kills the
//    two quarter-rate transcendentals/eval that were R6's issue floor.
//    |u| = |x*av/8| <= ~2.6 for this data; clamp covers the rest.
//  * NO local arrays (R9: promote-alloca left wox[]/wdy[] in scratch ->
//    859 MB FETCH, VALUBusy 24%). Weights stay in LDS like R6 (VGPR 60,
//    clean): one ds_read_b64 per step serves both samples.
//  * launch_bounds(256,4): 128-VGPR headroom; occupancy is LDS-bound at
//    ~25 KB -> 6 blocks/CU = 6 waves/SIMD (R6 had 4).

__device__ __forceinline__ float wave_ror1_f32(float v) {
    // D[i] = S[(i-1) & 63] — values move toward higher lanes
    return __int_as_float(__builtin_amdgcn_update_dpp(
        __float_as_int(v), __float_as_int(v), 0x13C, 0xF, 0xF, false));
}

// tanh(x * av / 8) by nearest lookup; as = 32*av so 256*(x*av/8) = x*as.
__device__ __forceinline__ float tanh_lut(const float* __restrict__ tb,
                                          float x, float as) {
    float idxf = fmaf(x, as, 1024.5f);                 // +0.5: round via trunc
    idxf = __builtin_amdgcn_fmed3f(idxf, 0.0f, 2047.0f);
    return tb[(int)idxf];
}

__global__ __launch_bounds__(256, 4) void cam_kernel(
    const float* __restrict__ f1,
    const float* __restrict__ f2,
    const float* __restrict__ Wca,
    const float* __restrict__ Wcv,
    float* __restrict__ out,
    int B)
{
    // s_Q[k][ln] = { W_{sel(ln)}[(ln+k)&63], W_{half((ln+k)&63)}[ln] }
    __shared__ __align__(16) float2 s_Q[32][64];       // 16 KB
    __shared__ float s_tanh[2048];                     // 8 KB

    const int tid  = threadIdx.x;
    const int lane = tid & 63;

    for (int i = tid; i < 2048; i += 256)              // tanh((i-1024)/256)
        s_tanh[i] = tanhf((float)(i - 1024) * 0.00390625f);

    for (int idx = tid; idx < 32 * 64; idx += 256) {
        const int k   = idx >> 6;
        const int ln  = idx & 63;
        const int sel = ln >> 5;
        const int j   = (ln + k) & 63;
        s_Q[k][ln] = make_float2((sel ? Wcv : Wca)[j],
                                 ((j < 32) ? Wca : Wcv)[ln]);
    }
    __syncthreads();

    const int sel = lane >> 5;                         // 0: audio, 1: visual
    const float* __restrict__ fbase = sel ? f2 : f1;
    const float* __restrict__ tb = s_tanh;
    const float2* __restrict__ Qp = &s_Q[0][lane];     // step k at Qp[k*64]
    const int col = lane & 31;

    const float w0  = (sel ? Wcv : Wca)[lane];         // k=0 (diagonal)
    const float w32 = (sel ? Wcv : Wca)[lane ^ 32];    // k=32
    const int idx31 = ((lane + 31) & 63) << 2;         // bpermute byte indices
    const int idx32 = (lane ^ 32) << 2;

    const int gw     = (blockIdx.x * 256 + tid) >> 6;
    const int stride = (gridDim.x << 2) * 2;           // 2 samples per wave/iter

    int b = gw * 2;
    if (b >= B) return;                                // wave-uniform
    float xA = fbase[b * 32 + col];
    float xB = (b + 1 < B) ? fbase[(b + 1) * 32 + col] : 0.0f;

    while (b < B) {
        const int bn = b + stride;
        float xnA = 0.0f, xnB = 0.0f;
        if (bn < B) {                                  // prefetch next pair
            xnA = fbase[bn * 32 + col];
            if (bn + 1 < B) xnB = fbase[(bn + 1) * 32 + col];
        }

        const float xsA = xA * 32.0f;                  // 32*av contribution
        const float xsB = xB * 32.0f;
        float aA = __int_as_float(                     // 32*x_{(r+31)&63}
            __builtin_amdgcn_ds_bpermute(idx31, __float_as_int(xsA)));
        float aB = __int_as_float(
            __builtin_amdgcn_ds_bpermute(idx31, __float_as_int(xsB)));
        const float a32A = __int_as_float(             // 32*x_{r^32}
            __builtin_amdgcn_ds_bpermute(idx32, __float_as_int(xsA)));
        const float a32B = __int_as_float(
            __builtin_amdgcn_ds_bpermute(idx32, __float_as_int(xsB)));

        // k=0 diagonal + k=32 (both lanes own-row), per sample
        float own0A = tanh_lut(tb, xA, xsA)  * w0;
        float own0B = tanh_lut(tb, xB, xsB)  * w0;
        float own1A = tanh_lut(tb, xA, a32A) * w32;
        float own1B = tanh_lut(tb, xB, a32B) * w32;

        float tA = 0.0f, tB = 0.0f;                    // traveling mirror accs
        #pragma unroll
        for (int k = 31; k >= 1; --k) {
            const float2 w2 = Qp[k * 64];              // ds_read_b64, imm offset
            const float pA = tanh_lut(tb, xA, aA);
            const float pB = tanh_lut(tb, xB, aB);
            if (k & 1) { own0A = fmaf(pA, w2.x, own0A); own0B = fmaf(pB, w2.x, own0B); }
            else       { own1A = fmaf(pA, w2.x, own1A); own1B = fmaf(pB, w2.x, own1B); }
            tA = wave_ror1_f32(fmaf(pA, w2.y, tA));
            aA = wave_ror1_f32(aA);
            tB = wave_ror1_f32(fmaf(pB, w2.y, tB));
            aB = wave_ror1_f32(aB);
        }
        // after the k=1 iteration each deposit has had exactly k rotations

        const float hA = fmaxf(xA + own0A + own1A + tA, 0.0f) * 0.1f;
        const float hB = fmaxf(xB + own0B + own1B + tB, 0.0f) * 0.1f;
        out[b * 64 + lane] = hA;
        if (b + 1 < B) out[(b + 1) * 64 + lane] = hB;

        b = bn;
        xA = xnA;
        xB = xnB;
    }
}

extern "C" void kernel_launch(void* const* d_in, const int* in_sizes, int n_in,
                              void* d_out, int out_size, void* d_ws, size_t ws_size,
                              hipStream_t stream) {
    const float* f1  = (const float*)d_in[0];
    const float* f2  = (const float*)d_in[1];
    const float* Wca = (const float*)d_in[2];
    const float* Wcv = (const float*)d_in[3];
    float* out = (float*)d_out;

    const int B = in_sizes[0] / 32;
    const int pairs = (B + 1) / 2;
    int blocks = (pairs + 3) / 4;       // 4 waves/block, 1 pair/wave minimum
    if (blocks > 1536) blocks = 1536;   // 6 blocks/CU (25 KB LDS) = 6 waves/SIMD
    if (blocks < 1) blocks = 1;

    cam_kernel<<<blocks, 256, 0, stream>>>(f1, f2, Wca, Wcv, out, B);
}